// Round 1
// baseline (503.765 us; speedup 1.0000x reference)
//
#include <hip/hip_runtime.h>
#include <math.h>

// Problem constants
#define B_SZ   1024
#define D_SZ   1024
#define H_SZ   16
#define DK_SZ  64
#define PHI_SZ 128   // 2*NU*DK, NU=1

// ---------------------------------------------------------------------------
// fp32 tiled GEMM: C[M,N] = A[M,K] @ B[K,N] (+ bias), 64x64 tile, 4x4 micro
// ---------------------------------------------------------------------------
__global__ __launch_bounds__(256) void gemm64(const float* __restrict__ A,
                                              const float* __restrict__ Bm,
                                              float* __restrict__ C,
                                              int M, int N, int K,
                                              const float* __restrict__ bias) {
  __shared__ __align__(16) float As[16][64];  // [k][m]
  __shared__ __align__(16) float Bs[16][64];  // [k][n]
  const int t  = threadIdx.x;
  const int bm = blockIdx.y * 64;
  const int bn = blockIdx.x * 64;
  const int tr = (t >> 4) * 4;   // micro-tile row
  const int tc = (t & 15) * 4;   // micro-tile col
  const int arow = t >> 2, akc = (t & 3) << 2;
  const int brow = t >> 4, bc  = (t & 15) << 2;
  float acc[4][4] = {};

  for (int k0 = 0; k0 < K; k0 += 16) {
    float4 a4 = *(const float4*)&A[(size_t)(bm + arow) * K + k0 + akc];
    As[akc + 0][arow] = a4.x;
    As[akc + 1][arow] = a4.y;
    As[akc + 2][arow] = a4.z;
    As[akc + 3][arow] = a4.w;
    *(float4*)&Bs[brow][bc] =
        *(const float4*)&Bm[(size_t)(k0 + brow) * N + bn + bc];
    __syncthreads();
#pragma unroll
    for (int kk = 0; kk < 16; ++kk) {
      const float4 a = *(const float4*)&As[kk][tr];
      const float4 b = *(const float4*)&Bs[kk][tc];
      const float av[4] = {a.x, a.y, a.z, a.w};
      const float bv[4] = {b.x, b.y, b.z, b.w};
#pragma unroll
      for (int i = 0; i < 4; ++i)
#pragma unroll
        for (int j = 0; j < 4; ++j) acc[i][j] = fmaf(av[i], bv[j], acc[i][j]);
    }
    __syncthreads();
  }

#pragma unroll
  for (int i = 0; i < 4; ++i) {
    float4 o = make_float4(acc[i][0], acc[i][1], acc[i][2], acc[i][3]);
    if (bias) {
      o.x += bias[bn + tc + 0];
      o.y += bias[bn + tc + 1];
      o.z += bias[bn + tc + 2];
      o.w += bias[bn + tc + 3];
    }
    *(float4*)&C[(size_t)(bm + tr + i) * N + bn + tc] = o;
  }
}

// ---------------------------------------------------------------------------
// gate: beta[b,h] = sigmoid(x[b,:] . Wg[:,h]);  Wg is [D,H] row-major
// ---------------------------------------------------------------------------
__global__ __launch_bounds__(256) void gate_kernel(const float* __restrict__ x,
                                                   const float* __restrict__ Wg,
                                                   float* __restrict__ beta) {
  __shared__ float xs[D_SZ];
  const int b = blockIdx.x;
  for (int i = threadIdx.x; i < D_SZ; i += 256) xs[i] = x[(size_t)b * D_SZ + i];
  __syncthreads();
  const int h = threadIdx.x >> 4;       // 0..15
  const int l16 = threadIdx.x & 15;     // 0..15
  float s = 0.f;
  for (int kk = l16; kk < D_SZ; kk += 16) s += xs[kk] * Wg[kk * H_SZ + h];
#pragma unroll
  for (int off = 8; off; off >>= 1) s += __shfl_down(s, off, 16);
  if (l16 == 0) beta[(size_t)b * H_SZ + h] = 1.f / (1.f + expf(-s));
}

// ---------------------------------------------------------------------------
// fast-weight kernel: one block per (b,h).
//   phi = dpfp(proj) for q,k;  v_exist = W.phik;  w_new = W + beta(v-v_exist)phik^T
//   out_h = w_new.phiq
// ---------------------------------------------------------------------------
__global__ __launch_bounds__(256) void fw_kernel(
    const float* __restrict__ qp, const float* __restrict__ kp,
    const float* __restrict__ vp, const float* __restrict__ beta_arr,
    const float* __restrict__ W_in, float* __restrict__ W_out,
    float* __restrict__ out_h) {
  const int bh = blockIdx.x;        // b*H + h
  const int t  = threadIdx.x;
  __shared__ __align__(16) float x2q[PHI_SZ];
  __shared__ __align__(16) float x2k[PHI_SZ];
  __shared__ __align__(16) float phiq[PHI_SZ];
  __shared__ __align__(16) float phik[PHI_SZ];
  __shared__ float vs[DK_SZ];
  __shared__ float red[2];
  __shared__ float sbeta;

  const int b = bh >> 4, h = bh & 15;
  const int pbase = b * (H_SZ * DK_SZ) + h * DK_SZ;

  if (t < DK_SZ) {
    float xq = qp[pbase + t];
    x2q[t] = fmaxf(xq, 0.f);
    x2q[t + DK_SZ] = fmaxf(-xq, 0.f);
    float xk = kp[pbase + t];
    x2k[t] = fmaxf(xk, 0.f);
    x2k[t + DK_SZ] = fmaxf(-xk, 0.f);
    vs[t] = vp[pbase + t];
  }
  if (t == 0) sbeta = beta_arr[bh];
  __syncthreads();

  if (t < PHI_SZ) {
    // y[i] = x2[i] * x2[(i-1) mod 128]  (roll by +1)
    phiq[t] = x2q[t] * x2q[(t + PHI_SZ - 1) & (PHI_SZ - 1)];
    phik[t] = x2k[t] * x2k[(t + PHI_SZ - 1) & (PHI_SZ - 1)];
  }
  __syncthreads();
  if (t < 64) {
    float sq = phiq[t] + phiq[t + 64];
    float sk = phik[t] + phik[t + 64];
#pragma unroll
    for (int off = 32; off; off >>= 1) {
      sq += __shfl_down(sq, off);
      sk += __shfl_down(sk, off);
    }
    if (t == 0) { red[0] = sq; red[1] = sk; }
  }
  __syncthreads();
  const float inv_sq = 1.f / (red[0] + 1e-6f);
  const float inv_sk = 1.f / (red[1] + 1e-6f);
  if (t < PHI_SZ) { phiq[t] *= inv_sq; phik[t] *= inv_sk; }
  __syncthreads();

  // 4 waves; each wave: 2 contiguous rows per pass (one per 32-lane half)
  const int wv = t >> 6;            // wave id 0..3
  const int l  = t & 63;
  const int half = l >> 5;          // 0/1
  const int sl = l & 31;            // 0..31
  const float beta = sbeta;
  const float* __restrict__ Wb  = W_in  + (size_t)bh * (DK_SZ * PHI_SZ);
  float* __restrict__       Wnb = W_out + (size_t)bh * (DK_SZ * PHI_SZ);

#pragma unroll
  for (int p = 0; p < 8; ++p) {
    const int r = p * 8 + wv * 2 + half;
    const float4 w4  = *(const float4*)&Wb[r * PHI_SZ + sl * 4];
    const float4 pk4 = *(const float4*)&phik[sl * 4];
    float ve = w4.x * pk4.x + w4.y * pk4.y + w4.z * pk4.z + w4.w * pk4.w;
#pragma unroll
    for (int off = 16; off; off >>= 1) ve += __shfl_xor(ve, off);
    const float dv = beta * (vs[r] - ve);
    float4 wn;
    wn.x = fmaf(dv, pk4.x, w4.x);
    wn.y = fmaf(dv, pk4.y, w4.y);
    wn.z = fmaf(dv, pk4.z, w4.z);
    wn.w = fmaf(dv, pk4.w, w4.w);
    *(float4*)&Wnb[r * PHI_SZ + sl * 4] = wn;
    const float4 pq4 = *(const float4*)&phiq[sl * 4];
    float oh = wn.x * pq4.x + wn.y * pq4.y + wn.z * pq4.z + wn.w * pq4.w;
#pragma unroll
    for (int off = 16; off; off >>= 1) oh += __shfl_xor(oh, off);
    if (sl == 0) out_h[pbase + r] = oh;
  }
}

// ---------------------------------------------------------------------------
extern "C" void kernel_launch(void* const* d_in, const int* in_sizes, int n_in,
                              void* d_out, int out_size, void* d_ws, size_t ws_size,
                              hipStream_t stream) {
  const float* x   = (const float*)d_in[0];
  const float* W0  = (const float*)d_in[1];  // weights [B,H,DK,PHI]
  const float* Wq  = (const float*)d_in[2];
  const float* Wk  = (const float*)d_in[3];
  const float* Wv  = (const float*)d_in[4];
  const float* Wg  = (const float*)d_in[5];
  const float* Wo  = (const float*)d_in[6];
  const float* bo  = (const float*)d_in[7];

  float* out   = (float*)d_out;                       // [B, D]
  float* w_new = out + (size_t)B_SZ * D_SZ;           // [B,H,DK,PHI]

  float* qp = (float*)d_ws;                           // [B, H*DK]
  float* kp = qp + (size_t)B_SZ * D_SZ;
  float* vp = kp + (size_t)B_SZ * D_SZ;
  float* oh = vp + (size_t)B_SZ * D_SZ;               // out_h [B, H*DK]
  float* bt = oh + (size_t)B_SZ * D_SZ;               // beta  [B, H]

  dim3 gg(D_SZ / 64, B_SZ / 64);
  gemm64<<<gg, 256, 0, stream>>>(x, Wq, qp, B_SZ, D_SZ, D_SZ, nullptr);
  gemm64<<<gg, 256, 0, stream>>>(x, Wk, kp, B_SZ, D_SZ, D_SZ, nullptr);
  gemm64<<<gg, 256, 0, stream>>>(x, Wv, vp, B_SZ, D_SZ, D_SZ, nullptr);
  gate_kernel<<<B_SZ, 256, 0, stream>>>(x, Wg, bt);
  fw_kernel<<<B_SZ * H_SZ, 256, 0, stream>>>(qp, kp, vp, bt, W0, w_new, oh);
  gemm64<<<gg, 256, 0, stream>>>(oh, Wo, out, B_SZ, D_SZ, D_SZ, bo);
}

// Round 2
// 305.437 us; speedup vs baseline: 1.6493x; 1.6493x over previous
//
#include <hip/hip_runtime.h>
#include <math.h>

// Problem constants
#define B_SZ   1024
#define D_SZ   1024
#define H_SZ   16
#define DK_SZ  64
#define PHI_SZ 128   // 2*NU*DK, NU=1

typedef __attribute__((ext_vector_type(8))) short short8;
typedef __attribute__((ext_vector_type(4))) float f32x4;

static __device__ __forceinline__ ushort f2b(float f) {
  union { float f; unsigned u; } v; v.f = f;
  unsigned r = v.u + 0x7fff + ((v.u >> 16) & 1);  // RNE
  return (ushort)(r >> 16);
}

// ---------------------------------------------------------------------------
// fp32 -> bf16 elementwise (n multiple of 2048)
// ---------------------------------------------------------------------------
__global__ __launch_bounds__(256) void convert_bf16(const float* __restrict__ in,
                                                    ushort* __restrict__ out, int n) {
  int i = (blockIdx.x * 256 + threadIdx.x) * 8;
  if (i >= n) return;
  float4 a = *(const float4*)&in[i];
  float4 b = *(const float4*)&in[i + 4];
  short8 o;
  o[0] = (short)f2b(a.x); o[1] = (short)f2b(a.y);
  o[2] = (short)f2b(a.z); o[3] = (short)f2b(a.w);
  o[4] = (short)f2b(b.x); o[5] = (short)f2b(b.y);
  o[6] = (short)f2b(b.z); o[7] = (short)f2b(b.w);
  *(short8*)&out[i] = o;
}

// ---------------------------------------------------------------------------
// W [K][N] fp32 row-major -> Wt [N][K] bf16 (64x64 tiles)
// ---------------------------------------------------------------------------
__global__ __launch_bounds__(256) void transpose_bf16(const float* __restrict__ W,
                                                      ushort* __restrict__ Wt,
                                                      int K, int N) {
  __shared__ ushort Ls[64][72];
  const int bk = blockIdx.x * 64;
  const int bn = blockIdx.y * 64;
  const int t = threadIdx.x;
  const int cq = (t & 15) * 4;
  const int r0 = t >> 4;
#pragma unroll
  for (int p = 0; p < 4; ++p) {
    const int kr = p * 16 + r0;
    float4 v = *(const float4*)&W[(size_t)(bk + kr) * N + bn + cq];
    Ls[cq + 0][kr] = f2b(v.x);
    Ls[cq + 1][kr] = f2b(v.y);
    Ls[cq + 2][kr] = f2b(v.z);
    Ls[cq + 3][kr] = f2b(v.w);
  }
  __syncthreads();
  const int nr = t >> 3;
  const int kk = (t & 7) * 8;
#pragma unroll
  for (int p = 0; p < 2; ++p) {
    const int n = p * 32 + nr;
    *(short8*)&Wt[(size_t)(bn + n) * K + bk + kk] = *(const short8*)&Ls[n][kk];
  }
}

// ---------------------------------------------------------------------------
// bf16 MFMA GEMM: C[M,N] (f32) = A[M,K] @ Bt[N,K]^T  (+bias)
// 64x64 tile, 4 waves (2x2), each wave 32x32 via 2x2 x mfma_f32_16x16x32_bf16
// ---------------------------------------------------------------------------
__global__ __launch_bounds__(256) void gemm_mfma(const ushort* __restrict__ A,
                                                 const ushort* __restrict__ Bt,
                                                 float* __restrict__ C,
                                                 int M, int N, int K,
                                                 const float* __restrict__ bias) {
  __shared__ __align__(16) ushort As[64 * 32];
  __shared__ __align__(16) ushort Bs[64 * 32];
  const int t = threadIdx.x;
  const int bm = blockIdx.y * 64;
  const int bn = blockIdx.x * 64;
  const int wid = t >> 6;
  const int l = t & 63;
  const int wr = (wid >> 1) * 32;
  const int wc = (wid & 1) * 32;
  const int row16 = l & 15;
  const int kg = l >> 4;  // 0..3

  // staging: thread t loads 8 bf16 of row (t>>2), k-group (t&3); XOR-swizzled dest
  const int srow = t >> 2;
  const int sg = t & 3;
  const int sw = sg ^ ((srow >> 1) & 3);
  const size_t a_src = (size_t)(bm + srow) * K + sg * 8;
  const size_t b_src = (size_t)(bn + srow) * K + sg * 8;
  ushort* a_dst = &As[srow * 32 + sw * 8];
  ushort* b_dst = &Bs[srow * 32 + sw * 8];

  f32x4 acc[2][2] = {};

  short8 ra = *(const short8*)&A[a_src];
  short8 rb = *(const short8*)&Bt[b_src];

  for (int k0 = 0; k0 < K; k0 += 32) {
    *(short8*)a_dst = ra;
    *(short8*)b_dst = rb;
    __syncthreads();
    if (k0 + 32 < K) {
      ra = *(const short8*)&A[a_src + k0 + 32];
      rb = *(const short8*)&Bt[b_src + k0 + 32];
    }
    short8 af[2], bf[2];
#pragma unroll
    for (int m = 0; m < 2; ++m) {
      const int ar = wr + m * 16 + row16;
      af[m] = *(const short8*)&As[ar * 32 + (kg ^ ((ar >> 1) & 3)) * 8];
      const int br = wc + m * 16 + row16;
      bf[m] = *(const short8*)&Bs[br * 32 + (kg ^ ((br >> 1) & 3)) * 8];
    }
#pragma unroll
    for (int m = 0; m < 2; ++m)
#pragma unroll
      for (int n = 0; n < 2; ++n)
        acc[m][n] = __builtin_amdgcn_mfma_f32_16x16x32_bf16(af[m], bf[n], acc[m][n], 0, 0, 0);
    __syncthreads();
  }

  const int crow0 = (l >> 4) * 4;
  const int ccol = l & 15;
#pragma unroll
  for (int m = 0; m < 2; ++m)
#pragma unroll
    for (int n = 0; n < 2; ++n) {
      const int col = bn + wc + n * 16 + ccol;
      const float bv = bias ? bias[col] : 0.f;
#pragma unroll
      for (int j = 0; j < 4; ++j) {
        const int rrow = bm + wr + m * 16 + crow0 + j;
        C[(size_t)rrow * N + col] = acc[m][n][j] + bv;
      }
    }
}

// ---------------------------------------------------------------------------
// gate: beta[b,h] = sigmoid(x[b,:] . Wg[:,h])
// ---------------------------------------------------------------------------
__global__ __launch_bounds__(256) void gate_kernel(const float* __restrict__ x,
                                                   const float* __restrict__ Wg,
                                                   float* __restrict__ beta) {
  __shared__ float xs[D_SZ];
  const int b = blockIdx.x;
  for (int i = threadIdx.x; i < D_SZ; i += 256) xs[i] = x[(size_t)b * D_SZ + i];
  __syncthreads();
  const int h = threadIdx.x >> 4;
  const int l16 = threadIdx.x & 15;
  float s = 0.f;
  for (int kk = l16; kk < D_SZ; kk += 16) s += xs[kk] * Wg[kk * H_SZ + h];
#pragma unroll
  for (int off = 8; off; off >>= 1) s += __shfl_down(s, off, 16);
  if (l16 == 0) beta[(size_t)b * H_SZ + h] = 1.f / (1.f + expf(-s));
}

// ---------------------------------------------------------------------------
// fast-weight kernel: one block per (b,h). out_h emitted as bf16.
// ---------------------------------------------------------------------------
__global__ __launch_bounds__(256) void fw_kernel(
    const float* __restrict__ qp, const float* __restrict__ kp,
    const float* __restrict__ vp, const float* __restrict__ beta_arr,
    const float* __restrict__ W_in, float* __restrict__ W_out,
    ushort* __restrict__ out_h) {
  const int bh = blockIdx.x;
  const int t  = threadIdx.x;
  __shared__ __align__(16) float x2q[PHI_SZ];
  __shared__ __align__(16) float x2k[PHI_SZ];
  __shared__ __align__(16) float phiq[PHI_SZ];
  __shared__ __align__(16) float phik[PHI_SZ];
  __shared__ float vs[DK_SZ];
  __shared__ float red[2];
  __shared__ float sbeta;

  const int b = bh >> 4, h = bh & 15;
  const int pbase = b * (H_SZ * DK_SZ) + h * DK_SZ;

  if (t < DK_SZ) {
    float xq = qp[pbase + t];
    x2q[t] = fmaxf(xq, 0.f);
    x2q[t + DK_SZ] = fmaxf(-xq, 0.f);
    float xk = kp[pbase + t];
    x2k[t] = fmaxf(xk, 0.f);
    x2k[t + DK_SZ] = fmaxf(-xk, 0.f);
    vs[t] = vp[pbase + t];
  }
  if (t == 0) sbeta = beta_arr[bh];
  __syncthreads();

  if (t < PHI_SZ) {
    phiq[t] = x2q[t] * x2q[(t + PHI_SZ - 1) & (PHI_SZ - 1)];
    phik[t] = x2k[t] * x2k[(t + PHI_SZ - 1) & (PHI_SZ - 1)];
  }
  __syncthreads();
  if (t < 64) {
    float sq = phiq[t] + phiq[t + 64];
    float sk = phik[t] + phik[t + 64];
#pragma unroll
    for (int off = 32; off; off >>= 1) {
      sq += __shfl_down(sq, off);
      sk += __shfl_down(sk, off);
    }
    if (t == 0) { red[0] = sq; red[1] = sk; }
  }
  __syncthreads();
  const float inv_sq = 1.f / (red[0] + 1e-6f);
  const float inv_sk = 1.f / (red[1] + 1e-6f);
  if (t < PHI_SZ) { phiq[t] *= inv_sq; phik[t] *= inv_sk; }
  __syncthreads();

  const int wv = t >> 6;
  const int l  = t & 63;
  const int half = l >> 5;
  const int sl = l & 31;
  const float beta = sbeta;
  const float* __restrict__ Wb  = W_in  + (size_t)bh * (DK_SZ * PHI_SZ);
  float* __restrict__       Wnb = W_out + (size_t)bh * (DK_SZ * PHI_SZ);

#pragma unroll
  for (int p = 0; p < 8; ++p) {
    const int r = p * 8 + wv * 2 + half;
    const float4 w4  = *(const float4*)&Wb[r * PHI_SZ + sl * 4];
    const float4 pk4 = *(const float4*)&phik[sl * 4];
    float ve = w4.x * pk4.x + w4.y * pk4.y + w4.z * pk4.z + w4.w * pk4.w;
#pragma unroll
    for (int off = 16; off; off >>= 1) ve += __shfl_xor(ve, off);
    const float dv = beta * (vs[r] - ve);
    float4 wn;
    wn.x = fmaf(dv, pk4.x, w4.x);
    wn.y = fmaf(dv, pk4.y, w4.y);
    wn.z = fmaf(dv, pk4.z, w4.z);
    wn.w = fmaf(dv, pk4.w, w4.w);
    *(float4*)&Wnb[r * PHI_SZ + sl * 4] = wn;
    const float4 pq4 = *(const float4*)&phiq[sl * 4];
    float oh = wn.x * pq4.x + wn.y * pq4.y + wn.z * pq4.z + wn.w * pq4.w;
#pragma unroll
    for (int off = 16; off; off >>= 1) oh += __shfl_xor(oh, off);
    if (sl == 0) out_h[pbase + r] = f2b(oh);
  }
}

// ---------------------------------------------------------------------------
extern "C" void kernel_launch(void* const* d_in, const int* in_sizes, int n_in,
                              void* d_out, int out_size, void* d_ws, size_t ws_size,
                              hipStream_t stream) {
  const float* x   = (const float*)d_in[0];
  const float* W0  = (const float*)d_in[1];
  const float* Wq  = (const float*)d_in[2];
  const float* Wk  = (const float*)d_in[3];
  const float* Wv  = (const float*)d_in[4];
  const float* Wg  = (const float*)d_in[5];
  const float* Wo  = (const float*)d_in[6];
  const float* bo  = (const float*)d_in[7];

  float* out   = (float*)d_out;                        // [B, D]
  float* w_new = out + (size_t)B_SZ * D_SZ;            // [B,H,DK,PHI]

  const size_t NE = (size_t)B_SZ * D_SZ;               // 1M
  float*  qp  = (float*)d_ws;
  float*  kp  = qp + NE;
  float*  vp  = kp + NE;
  float*  bt  = vp + NE;                               // beta [B,H]
  ushort* xb  = (ushort*)(bt + (size_t)B_SZ * H_SZ);
  ushort* wqT = xb + NE;
  ushort* wkT = wqT + NE;
  ushort* wvT = wkT + NE;
  ushort* woT = wvT + NE;
  ushort* ohb = woT + NE;                              // out_h bf16 [B, H*DK]

  convert_bf16<<<NE / 2048, 256, 0, stream>>>(x, xb, (int)NE);

  dim3 tg(D_SZ / 64, D_SZ / 64);
  transpose_bf16<<<tg, 256, 0, stream>>>(Wq, wqT, D_SZ, D_SZ);
  transpose_bf16<<<tg, 256, 0, stream>>>(Wk, wkT, D_SZ, D_SZ);
  transpose_bf16<<<tg, 256, 0, stream>>>(Wv, wvT, D_SZ, D_SZ);
  transpose_bf16<<<tg, 256, 0, stream>>>(Wo, woT, D_SZ, D_SZ);

  dim3 gg(D_SZ / 64, B_SZ / 64);
  gemm_mfma<<<gg, 256, 0, stream>>>(xb, wqT, qp, B_SZ, D_SZ, D_SZ, nullptr);
  gemm_mfma<<<gg, 256, 0, stream>>>(xb, wkT, kp, B_SZ, D_SZ, D_SZ, nullptr);
  gemm_mfma<<<gg, 256, 0, stream>>>(xb, wvT, vp, B_SZ, D_SZ, D_SZ, nullptr);
  gate_kernel<<<B_SZ, 256, 0, stream>>>(x, Wg, bt);
  fw_kernel<<<B_SZ * H_SZ, 256, 0, stream>>>(qp, kp, vp, bt, W0, w_new, ohb);
  gemm_mfma<<<gg, 256, 0, stream>>>(ohb, woT, out, B_SZ, D_SZ, D_SZ, bo);
}

// Round 3
// 279.177 us; speedup vs baseline: 1.8045x; 1.0941x over previous
//
#include <hip/hip_runtime.h>
#include <math.h>

// Problem constants
#define B_SZ   1024
#define D_SZ   1024
#define H_SZ   16
#define DK_SZ  64
#define PHI_SZ 128   // 2*NU*DK, NU=1

typedef __attribute__((ext_vector_type(8))) short short8;
typedef __attribute__((ext_vector_type(4))) float f32x4;

static __device__ __forceinline__ ushort f2b(float f) {
  union { float f; unsigned u; } v; v.f = f;
  unsigned r = v.u + 0x7fff + ((v.u >> 16) & 1);  // RNE
  return (ushort)(r >> 16);
}

// ---------------------------------------------------------------------------
// fp32 -> bf16 elementwise (n multiple of 2048)
// ---------------------------------------------------------------------------
__global__ __launch_bounds__(256) void convert_bf16(const float* __restrict__ in,
                                                    ushort* __restrict__ out, int n) {
  int i = (blockIdx.x * 256 + threadIdx.x) * 8;
  if (i >= n) return;
  float4 a = *(const float4*)&in[i];
  float4 b = *(const float4*)&in[i + 4];
  short8 o;
  o[0] = (short)f2b(a.x); o[1] = (short)f2b(a.y);
  o[2] = (short)f2b(a.z); o[3] = (short)f2b(a.w);
  o[4] = (short)f2b(b.x); o[5] = (short)f2b(b.y);
  o[6] = (short)f2b(b.z); o[7] = (short)f2b(b.w);
  *(short8*)&out[i] = o;
}

// ---------------------------------------------------------------------------
// 4-way transpose: W[z] [1024][1024] fp32 -> dst + z*1M as [N][K] bf16
// ---------------------------------------------------------------------------
__global__ __launch_bounds__(256) void transpose4(const float* __restrict__ s0,
                                                  const float* __restrict__ s1,
                                                  const float* __restrict__ s2,
                                                  const float* __restrict__ s3,
                                                  ushort* __restrict__ dst) {
  __shared__ ushort Ls[64][80];
  const float* srcs[4] = {s0, s1, s2, s3};
  const float* __restrict__ W = srcs[blockIdx.z];
  ushort* __restrict__ Wt = dst + (size_t)blockIdx.z * (D_SZ * D_SZ);
  const int K = D_SZ, N = D_SZ;
  const int bk = blockIdx.x * 64;
  const int bn = blockIdx.y * 64;
  const int t = threadIdx.x;
  const int cq = (t & 15) * 4;
  const int r0 = t >> 4;
#pragma unroll
  for (int p = 0; p < 4; ++p) {
    const int kr = p * 16 + r0;
    float4 v = *(const float4*)&W[(size_t)(bk + kr) * N + bn + cq];
    Ls[cq + 0][kr] = f2b(v.x);
    Ls[cq + 1][kr] = f2b(v.y);
    Ls[cq + 2][kr] = f2b(v.z);
    Ls[cq + 3][kr] = f2b(v.w);
  }
  __syncthreads();
  const int nr = t >> 3;
  const int kk = (t & 7) * 8;
#pragma unroll
  for (int p = 0; p < 2; ++p) {
    const int n = p * 32 + nr;
    *(short8*)&Wt[(size_t)(bn + n) * K + bk + kk] = *(const short8*)&Ls[n][kk];
  }
}

// ---------------------------------------------------------------------------
// bf16 MFMA GEMM: C[M,N] (f32) = A[M,K] @ Bt[N,K]^T (+bias)
// BM=64 x BN tile, 4 waves (2x2), wave tile 32 x BN/2, BK=32
// ---------------------------------------------------------------------------
template <int BN>
__global__ __launch_bounds__(256) void gemm_mfma(const ushort* __restrict__ A,
                                                 const ushort* __restrict__ Bt,
                                                 float* __restrict__ C,
                                                 int M, int N, int K,
                                                 const float* __restrict__ bias) {
  constexpr int NB = BN / 2;        // wave tile cols
  constexpr int NF = NB / 16;       // B-frags per wave
  constexpr int BITER = BN * 4 / 256;
  __shared__ __align__(16) ushort As[64 * 32];
  __shared__ __align__(16) ushort Bs[BN * 32];
  const int t = threadIdx.x;
  const int bm = blockIdx.y * 64;
  const int bn = blockIdx.x * BN;
  const int wid = t >> 6;
  const int l = t & 63;
  const int wr = (wid >> 1) * 32;
  const int wc = (wid & 1) * NB;
  const int row16 = l & 15;
  const int kg = l >> 4;

  const int sr = t >> 2;
  const int sg = t & 3;
  const size_t a_src = (size_t)(bm + sr) * K + sg * 8;
  ushort* a_dst = &As[sr * 32 + (sg ^ ((sr >> 1) & 3)) * 8];
  size_t b_src[BITER];
  ushort* b_dst[BITER];
#pragma unroll
  for (int i = 0; i < BITER; ++i) {
    const int br = sr + i * 64;
    b_src[i] = (size_t)(bn + br) * K + sg * 8;
    b_dst[i] = &Bs[br * 32 + (sg ^ ((br >> 1) & 3)) * 8];
  }

  f32x4 acc[2][NF] = {};

  short8 ra = *(const short8*)&A[a_src];
  short8 rb[BITER];
#pragma unroll
  for (int i = 0; i < BITER; ++i) rb[i] = *(const short8*)&Bt[b_src[i]];

  for (int k0 = 0; k0 < K; k0 += 32) {
    *(short8*)a_dst = ra;
#pragma unroll
    for (int i = 0; i < BITER; ++i) *(short8*)b_dst[i] = rb[i];
    __syncthreads();
    if (k0 + 32 < K) {
      ra = *(const short8*)&A[a_src + k0 + 32];
#pragma unroll
      for (int i = 0; i < BITER; ++i) rb[i] = *(const short8*)&Bt[b_src[i] + k0 + 32];
    }
    short8 af[2], bf[NF];
#pragma unroll
    for (int m = 0; m < 2; ++m) {
      const int ar = wr + m * 16 + row16;
      af[m] = *(const short8*)&As[ar * 32 + (kg ^ ((ar >> 1) & 3)) * 8];
    }
#pragma unroll
    for (int n = 0; n < NF; ++n) {
      const int br = wc + n * 16 + row16;
      bf[n] = *(const short8*)&Bs[br * 32 + (kg ^ ((br >> 1) & 3)) * 8];
    }
#pragma unroll
    for (int m = 0; m < 2; ++m)
#pragma unroll
      for (int n = 0; n < NF; ++n)
        acc[m][n] = __builtin_amdgcn_mfma_f32_16x16x32_bf16(af[m], bf[n], acc[m][n], 0, 0, 0);
    __syncthreads();
  }

  const int crow0 = (l >> 4) * 4;
  const int ccol = l & 15;
#pragma unroll
  for (int m = 0; m < 2; ++m)
#pragma unroll
    for (int n = 0; n < NF; ++n) {
      const int col = bn + wc + n * 16 + ccol;
      const float bv = bias ? bias[col] : 0.f;
#pragma unroll
      for (int j = 0; j < 4; ++j) {
        const int rrow = bm + wr + m * 16 + crow0 + j;
        C[(size_t)rrow * N + col] = acc[m][n][j] + bv;
      }
    }
}

// ---------------------------------------------------------------------------
// gate: beta[b,h] = sigmoid(x[b,:] . Wg[:,h])
// ---------------------------------------------------------------------------
__global__ __launch_bounds__(256) void gate_kernel(const float* __restrict__ x,
                                                   const float* __restrict__ Wg,
                                                   float* __restrict__ beta) {
  __shared__ float xs[D_SZ];
  const int b = blockIdx.x;
  for (int i = threadIdx.x; i < D_SZ; i += 256) xs[i] = x[(size_t)b * D_SZ + i];
  __syncthreads();
  const int h = threadIdx.x >> 4;
  const int l16 = threadIdx.x & 15;
  float s = 0.f;
  for (int kk = l16; kk < D_SZ; kk += 16) s += xs[kk] * Wg[kk * H_SZ + h];
#pragma unroll
  for (int off = 8; off; off >>= 1) s += __shfl_down(s, off, 16);
  if (l16 == 0) beta[(size_t)b * H_SZ + h] = 1.f / (1.f + expf(-s));
}

// ---------------------------------------------------------------------------
// fast-weight kernel: one block per (b,h). qkv is [B][3072] (q|k|v).
// W prefetched before prologue; per-wave redundant phi reduction (no extra
// barriers); out_h gathered in LDS and stored coalesced as bf16.
// ---------------------------------------------------------------------------
__global__ __launch_bounds__(256) void fw_kernel(
    const float* __restrict__ qkv, const float* __restrict__ beta_arr,
    const float* __restrict__ W_in, float* __restrict__ W_out,
    ushort* __restrict__ out_h) {
  const int bh = blockIdx.x;
  const int t  = threadIdx.x;
  const int b = bh >> 4, h = bh & 15;
  const int wv = t >> 6;
  const int l  = t & 63;
  const int half = l >> 5;
  const int sl = l & 31;

  const float* __restrict__ Wb  = W_in  + (size_t)bh * (DK_SZ * PHI_SZ);
  float* __restrict__       Wnb = W_out + (size_t)bh * (DK_SZ * PHI_SZ);

  // prefetch all 8 W rows for this thread before the prologue barriers
  float4 w[8];
#pragma unroll
  for (int p = 0; p < 8; ++p) {
    const int r = p * 8 + wv * 2 + half;
    w[p] = *(const float4*)&Wb[r * PHI_SZ + sl * 4];
  }
  const float beta = beta_arr[bh];

  __shared__ __align__(16) float x2q[PHI_SZ];
  __shared__ __align__(16) float x2k[PHI_SZ];
  __shared__ __align__(16) float phiq[PHI_SZ];
  __shared__ __align__(16) float phik[PHI_SZ];
  __shared__ float vs[DK_SZ];
  __shared__ __align__(16) float ohs[DK_SZ];

  const int qb = b * (3 * D_SZ) + h * DK_SZ;
  if (t < DK_SZ) {
    float xq = qkv[qb + t];
    float xk = qkv[qb + D_SZ + t];
    x2q[t] = fmaxf(xq, 0.f);
    x2q[t + DK_SZ] = fmaxf(-xq, 0.f);
    x2k[t] = fmaxf(xk, 0.f);
    x2k[t + DK_SZ] = fmaxf(-xk, 0.f);
    vs[t] = qkv[qb + 2 * D_SZ + t];
  }
  __syncthreads();
  if (t < PHI_SZ) {
    phiq[t] = x2q[t] * x2q[(t + PHI_SZ - 1) & (PHI_SZ - 1)];
    phik[t] = x2k[t] * x2k[(t + PHI_SZ - 1) & (PHI_SZ - 1)];
  }
  __syncthreads();

  // per-wave redundant reduction over the 128 phi values
  float sq = phiq[l] + phiq[l + 64];
  float sk = phik[l] + phik[l + 64];
#pragma unroll
  for (int off = 32; off; off >>= 1) {
    sq += __shfl_xor(sq, off);
    sk += __shfl_xor(sk, off);
  }
  const float inv_sq = 1.f / (sq + 1e-6f);
  const float inv_sk = 1.f / (sk + 1e-6f);

  // loop-invariant normalized phi fragments (registers)
  float4 pq4 = *(const float4*)&phiq[sl * 4];
  float4 pk4 = *(const float4*)&phik[sl * 4];
  pq4.x *= inv_sq; pq4.y *= inv_sq; pq4.z *= inv_sq; pq4.w *= inv_sq;
  pk4.x *= inv_sk; pk4.y *= inv_sk; pk4.z *= inv_sk; pk4.w *= inv_sk;

#pragma unroll
  for (int p = 0; p < 8; ++p) {
    const int r = p * 8 + wv * 2 + half;
    float ve = w[p].x * pk4.x + w[p].y * pk4.y + w[p].z * pk4.z + w[p].w * pk4.w;
#pragma unroll
    for (int off = 16; off; off >>= 1) ve += __shfl_xor(ve, off);
    const float dv = beta * (vs[r] - ve);
    float4 wn;
    wn.x = fmaf(dv, pk4.x, w[p].x);
    wn.y = fmaf(dv, pk4.y, w[p].y);
    wn.z = fmaf(dv, pk4.z, w[p].z);
    wn.w = fmaf(dv, pk4.w, w[p].w);
    *(float4*)&Wnb[r * PHI_SZ + sl * 4] = wn;
    float oh = wn.x * pq4.x + wn.y * pq4.y + wn.z * pq4.z + wn.w * pq4.w;
#pragma unroll
    for (int off = 16; off; off >>= 1) oh += __shfl_xor(oh, off);
    if (sl == 0) ohs[r] = oh;
  }
  __syncthreads();
  if (t < 8) {
    short8 o;
#pragma unroll
    for (int j = 0; j < 8; ++j) o[j] = (short)f2b(ohs[t * 8 + j]);
    *(short8*)&out_h[(size_t)b * D_SZ + h * DK_SZ + t * 8] = o;
  }
}

// ---------------------------------------------------------------------------
extern "C" void kernel_launch(void* const* d_in, const int* in_sizes, int n_in,
                              void* d_out, int out_size, void* d_ws, size_t ws_size,
                              hipStream_t stream) {
  const float* x   = (const float*)d_in[0];
  const float* W0  = (const float*)d_in[1];
  const float* Wq  = (const float*)d_in[2];
  const float* Wk  = (const float*)d_in[3];
  const float* Wv  = (const float*)d_in[4];
  const float* Wg  = (const float*)d_in[5];
  const float* Wo  = (const float*)d_in[6];
  const float* bo  = (const float*)d_in[7];

  float* out   = (float*)d_out;                        // [B, D]
  float* w_new = out + (size_t)B_SZ * D_SZ;            // [B,H,DK,PHI]

  const size_t NE = (size_t)B_SZ * D_SZ;               // 1M
  float*  qkv = (float*)d_ws;                          // [B][3*D] fp32
  float*  bt  = qkv + 3 * NE;                          // beta [B,H]
  ushort* xb  = (ushort*)(bt + (size_t)B_SZ * H_SZ);   // x bf16
  ushort* wall = xb + NE;                              // wqT|wkT|wvT|woT bf16
  ushort* ohb  = wall + 4 * NE;                        // out_h bf16

  convert_bf16<<<NE / 2048, 256, 0, stream>>>(x, xb, (int)NE);

  dim3 tg(D_SZ / 64, D_SZ / 64, 4);
  transpose4<<<tg, 256, 0, stream>>>(Wq, Wk, Wv, Wo, wall);

  gate_kernel<<<B_SZ, 256, 0, stream>>>(x, Wg, bt);

  // fused q|k|v projection: [1024,1024] @ [1024,3072] -> qkv
  dim3 g1(3 * D_SZ / 128, B_SZ / 64);
  gemm_mfma<128><<<g1, 256, 0, stream>>>(xb, wall, qkv, B_SZ, 3 * D_SZ, D_SZ, nullptr);

  fw_kernel<<<B_SZ * H_SZ, 256, 0, stream>>>(qkv, bt, W0, w_new, ohb);

  dim3 g2(D_SZ / 64, B_SZ / 64);
  gemm_mfma<64><<<g2, 256, 0, stream>>>(ohb, wall + 3 * NE, out, B_SZ, D_SZ, D_SZ, bo);
}